// Round 17
// baseline (44.054 us; speedup 1.0000x reference)
//
#include <hip/hip_runtime.h>
#include <hip/hip_bf16.h>

// Problem constants (match reference)
#define BB 16384
#define DD 512
#define NCLS 90
#define KC 32
#define BUCKET 512   // max samples per class (mean 182, +24 sigma headroom)
#define PRB 180      // center-norm blocks in k_prep (2880 rows / 16 waves)
#define NP 8         // chunk-slots per class (chunk = 16 samples), grid 720

typedef __attribute__((ext_vector_type(8))) short short8;   // 8 bf16 (4 VGPRs)
typedef __attribute__((ext_vector_type(4))) float fx4;      // MFMA accumulator

static __device__ __forceinline__ short f2bf(float f) {
    unsigned u = __float_as_uint(f);
    unsigned r = (u + 0x7fffu + ((u >> 16) & 1u)) >> 16;    // RNE
    return (short)r;
}
// pack 8 f32 -> 8 bf16 (RNE, v_cvt_pk_bf16_f32)
static __device__ __forceinline__ short8 pack8(float4 a, float4 b) {
    union { __hip_bfloat162 h[4]; short8 s; } u;
    u.h[0] = __float22bfloat162_rn(make_float2(a.x, a.y));
    u.h[1] = __float22bfloat162_rn(make_float2(a.z, a.w));
    u.h[2] = __float22bfloat162_rn(make_float2(b.x, b.y));
    u.h[3] = __float22bfloat162_rn(make_float2(b.z, b.w));
    return u.s;
}
static __device__ __forceinline__ void gload_lds16(const void* g, void* l) {
    __builtin_amdgcn_global_load_lds(
        (const __attribute__((address_space(1))) void*)g,
        (__attribute__((address_space(3))) void*)l, 16, 0, 0);
}

// ------- kernel 1: prep (R9-verbatim) + counter re-arm -----------------------
__global__ __launch_bounds__(1024)
void k_prep(const float* __restrict__ centers, const int* __restrict__ labels,
            short* __restrict__ cni, int* __restrict__ idx, int* __restrict__ cnt,
            int* __restrict__ counter) {
    __shared__ int lab[BB];       // 64 KiB label cache for binning blocks
    __shared__ int wcnt[16];

    int t = threadIdx.x, w = t >> 6, lane = t & 63;

    if ((int)blockIdx.x < PRB) {
        int row = blockIdx.x * 16 + w;                  // 0..2879
        const float4* p = (const float4*)(centers + (size_t)row * DD);
        float4 a = p[lane * 2];
        float4 b = p[lane * 2 + 1];
        float s = a.x * a.x + a.y * a.y + a.z * a.z + a.w * a.w
                + b.x * b.x + b.y * b.y + b.z * b.z + b.w * b.w;
#pragma unroll
        for (int m = 1; m < 64; m <<= 1) s += __shfl_xor(s, m, 64);
        float sc = rsqrtf(s + 1e-12f);
        short8 v;
        v[0] = f2bf(a.x * sc); v[1] = f2bf(a.y * sc);
        v[2] = f2bf(a.z * sc); v[3] = f2bf(a.w * sc);
        v[4] = f2bf(b.x * sc); v[5] = f2bf(b.y * sc);
        v[6] = f2bf(b.z * sc); v[7] = f2bf(b.w * sc);
        *(short8*)(cni + (size_t)row * DD + lane * 8) = v;
    } else {
        int c = blockIdx.x - PRB;
        if (c == 0 && t == 0) *counter = 0;             // re-arm every call
        for (int j = t; j < BB / 4; j += 1024)
            ((int4*)lab)[j] = ((const int4*)labels)[j];
        __syncthreads();

        int seg4 = w * (BB / 4 / 16);
        int cw = 0;
#pragma unroll
        for (int jj = 0; jj < 4; jj++) {
            int4 v = ((int4*)lab)[seg4 + jj * 64 + lane];
            cw += (v.x == c) + (v.y == c) + (v.z == c) + (v.w == c);
        }
#pragma unroll
        for (int m = 1; m < 64; m <<= 1) cw += __shfl_xor(cw, m, 64);
        if (lane == 0) wcnt[w] = cw;
        __syncthreads();
        int pos = c * BUCKET;
        for (int ww = 0; ww < w; ww++) pos += wcnt[ww];
#pragma unroll
        for (int jj = 0; jj < 4; jj++) {
            int4 v = ((int4*)lab)[seg4 + jj * 64 + lane];
            int gbase = (seg4 + jj * 64 + lane) * 4;
            { bool m = (v.x == c); unsigned long long k = __ballot(m);
              if (m) idx[pos + __popcll(k & ((1ull << lane) - 1ull))] = gbase;     pos += __popcll(k); }
            { bool m = (v.y == c); unsigned long long k = __ballot(m);
              if (m) idx[pos + __popcll(k & ((1ull << lane) - 1ull))] = gbase + 1; pos += __popcll(k); }
            { bool m = (v.z == c); unsigned long long k = __ballot(m);
              if (m) idx[pos + __popcll(k & ((1ull << lane) - 1ull))] = gbase + 2; pos += __popcll(k); }
            { bool m = (v.w == c); unsigned long long k = __ballot(m);
              if (m) idx[pos + __popcll(k & ((1ull << lane) - 1ull))] = gbase + 3; pos += __popcll(k); }
        }
        if (t == 0) {
            int s = 0;
#pragma unroll
            for (int i = 0; i < 16; i++) s += wcnt[i];
            cnt[c] = s;
        }
    }
}

// ------- kernel 2: main — 16-sample chunks, k-split waves, 3 blocks/CU -------
// LDS 53.6 KB -> 3 blocks/CU (12 waves/CU). Wave w: k-half kh=w>>1 (k chunks
// kh*32..+31), center-half chf=w&1. Partial dots combined in S (R12-verified).
// Last block does the deterministic final mean (R5-verified pattern).
__launch_bounds__(256, 3)
__global__ void k_main(const float* __restrict__ x,
                       const short* __restrict__ cni,
                       const int* __restrict__ cnt,
                       const int* __restrict__ idx,
                       float* __restrict__ partials,
                       int* __restrict__ counter,
                       float* __restrict__ out) {
    __shared__ __align__(16) short c_lds[KC * DD];   // 32768 B, XOR-swizzled
    __shared__ __align__(16) short x_lds[16 * DD];   // 16384 B, XOR-swizzled
    __shared__ float S[2][16][34];                   //  4352 B: k-half partials
    __shared__ float xinv[16];
    __shared__ float red4[4];
    __shared__ int lastflag;

    int b = blockIdx.x;
    int c = b >> 3, p = b & 7;
    int n = cnt[c];
    int nch = (n + 15) >> 4;
    int t = threadIdx.x, w = t >> 6, lane = t & 63;
    float loss_acc = 0.f;

    if (p < nch) {
        // ---- stage class centers (bf16 image) via async DMA, source-swizzled
        const short* cbase = cni + (size_t)c * KC * DD;
#pragma unroll
        for (int it = 0; it < 8; it++) {
            int q = t + 256 * it;                 // 16B chunk 0..2047, linear LDS
            int drow = q >> 6, cc = q & 63;
            gload_lds16(cbase + drow * DD + (cc ^ (drow & 7)) * 8, &c_lds[q * 8]);
        }

        int base = c * BUCKET;
        int row16 = t >> 4, l16 = t & 15;         // staging/softmax: 16 thr/row
        int r = lane & 15, g4 = lane >> 4;
        int kh = w >> 1, chf = w & 1;             // k-half, center-half
        int brow = (chf << 4) + r;                // center row in c_lds

        for (int ch = p; ch < nch; ch += NP) {
            int off = ch << 4;
            int rem = n - off;                    // > 0

            // ---- gather raw f32 x row: issue all 8 loads first (T14) ----
            {
                int i = off + row16; if (i > n - 1) i = n - 1;
                int g = idx[base + i];
                const float4* src = (const float4*)(x + (size_t)g * DD);
                float4 va[4], vb[4];
#pragma unroll
                for (int jj = 0; jj < 4; jj++) {   // 8 independent 16B loads
                    va[jj] = src[2 * l16 + 32 * jj];
                    vb[jj] = src[2 * l16 + 32 * jj + 1];
                }
                float nrm = 0.f;
#pragma unroll
                for (int jj = 0; jj < 4; jj++) {   // use phase: norm + cvt + LDS
                    int cc = l16 + 16 * jj;        // 16B bf16 chunk 0..63
                    float4 a = va[jj], b4 = vb[jj];
                    nrm += a.x * a.x + a.y * a.y + a.z * a.z + a.w * a.w
                         + b4.x * b4.x + b4.y * b4.y + b4.z * b4.z + b4.w * b4.w;
                    *(short8*)&x_lds[row16 * DD + ((cc ^ (row16 & 7)) << 3)] = pack8(a, b4);
                }
#pragma unroll
                for (int m = 1; m < 16; m <<= 1) nrm += __shfl_xor(nrm, m, 64);
                if (l16 == 0) xinv[row16] = rsqrtf(nrm + 1e-12f);
            }
            __syncthreads();                       // drains DMA + ds_writes

            // ---- MFMA: 8 k-steps of this wave's k-half, center half chf ----
            fx4 acc = {0.f, 0.f, 0.f, 0.f};
#pragma unroll
            for (int ks = 0; ks < 8; ks++) {
                int c16a = kh * 32 + ks * 4 + g4;
                short8 av = *(const short8*)&x_lds[r * DD + ((c16a ^ (r & 7)) << 3)];
                short8 bv = *(const short8*)&c_lds[brow * DD + ((c16a ^ (brow & 7)) << 3)];
                acc = __builtin_amdgcn_mfma_f32_16x16x32_bf16(av, bv, acc, 0, 0, 0);
            }
#pragma unroll
            for (int j = 0; j < 4; j++)            // D: sample=(g4*4+j), center=r
                S[kh][(g4 << 2) + j][(chf << 4) + r] = acc[j];
            __syncthreads();

            // ---- combine k-halves + MAX-FREE softmax (cos in [-1,1]) ----
            {
                float xv = xinv[row16];
                int c0 = l16 * 2;
                float sa = (S[0][row16][c0]     + S[1][row16][c0])     * xv;
                float sb = (S[0][row16][c0 + 1] + S[1][row16][c0 + 1]) * xv;
                float ea = __expf(sa), eb = __expf(sb);
                float Z = ea + eb;
                float num = ea * (1.f - sa) + eb * (1.f - sb);
#pragma unroll
                for (int m = 1; m < 16; m <<= 1) {
                    Z   += __shfl_xor(Z, m, 64);
                    num += __shfl_xor(num, m, 64);
                }
                if (l16 == 0 && row16 < rem) loss_acc += num / Z;
            }
            __syncthreads();   // protect x_lds/S/xinv before next chunk
        }
    }

    // ---- block partial + deterministic last-block final mean ----
#pragma unroll
    for (int m = 1; m < 64; m <<= 1) loss_acc += __shfl_xor(loss_acc, m, 64);
    if (lane == 0) red4[w] = loss_acc;
    __syncthreads();
    if (t == 0) {
        partials[b] = red4[0] + red4[1] + red4[2] + red4[3];
        __threadfence();                           // publish partial
        int old = atomicAdd(counter, 1);
        lastflag = (old == (int)gridDim.x - 1);
    }
    __syncthreads();
    if (lastflag) {
        __threadfence();
        float s = 0.f;
        for (int i = t; i < NCLS * NP; i += 256)
            s += __hip_atomic_load(&partials[i], __ATOMIC_RELAXED, __HIP_MEMORY_SCOPE_AGENT);
#pragma unroll
        for (int m = 1; m < 64; m <<= 1) s += __shfl_xor(s, m, 64);
        if (lane == 0) red4[w] = s;
        __syncthreads();
        if (t == 0) out[0] = (red4[0] + red4[1] + red4[2] + red4[3]) * (1.0f / (float)BB);
    }
}

extern "C" void kernel_launch(void* const* d_in, const int* in_sizes, int n_in,
                              void* d_out, int out_size, void* d_ws, size_t ws_size,
                              hipStream_t stream) {
    const float* x       = (const float*)d_in[0];
    const int*   labels  = (const int*)d_in[1];
    const float* centers = (const float*)d_in[2];
    float* out = (float*)d_out;

    char* ws = (char*)d_ws;
    short* cni      = (short*)(ws + 0);             // 2880*512 bf16 = 2,949,120 B
    int*   idx      = (int*)(ws + 3145728);         // 90*512 ints   =   184,320 B
    int*   cnt      = (int*)(ws + 3407872);         // 90 ints
    int*   counter  = (int*)(ws + 3408384);         // 1 int (re-armed by k_prep)
    float* partials = (float*)(ws + 3473408);       // 720 floats (all written)

    k_prep<<<PRB + NCLS, 1024, 0, stream>>>(centers, labels, cni, idx, cnt, counter);
    k_main<<<NCLS * NP, 256, 0, stream>>>(x, cni, cnt, idx, partials, counter, out);
}

// Round 18
// 28.595 us; speedup vs baseline: 1.5406x; 1.5406x over previous
//
#include <hip/hip_runtime.h>
#include <hip/hip_bf16.h>

// Problem constants (match reference)
#define BB 16384
#define DD 512
#define NCLS 90
#define KC 32
#define BUCKET 512   // max samples per class (mean 182, +24 sigma headroom)
#define NP 8         // partition blocks per class (chunk = 32 samples)

typedef __attribute__((ext_vector_type(8))) short short8;   // 8 bf16 (4 VGPRs)
typedef __attribute__((ext_vector_type(4))) float fx4;      // MFMA accumulator

// pack 8 f32 -> 8 bf16 (RNE, v_cvt_pk_bf16_f32), with / without scale
static __device__ __forceinline__ short8 pack8s(float sc, float4 a, float4 b) {
    union { __hip_bfloat162 h[4]; short8 s; } u;
    u.h[0] = __float22bfloat162_rn(make_float2(a.x * sc, a.y * sc));
    u.h[1] = __float22bfloat162_rn(make_float2(a.z * sc, a.w * sc));
    u.h[2] = __float22bfloat162_rn(make_float2(b.x * sc, b.y * sc));
    u.h[3] = __float22bfloat162_rn(make_float2(b.z * sc, b.w * sc));
    return u.s;
}
static __device__ __forceinline__ short8 pack8(float4 a, float4 b) {
    union { __hip_bfloat162 h[4]; short8 s; } u;
    u.h[0] = __float22bfloat162_rn(make_float2(a.x, a.y));
    u.h[1] = __float22bfloat162_rn(make_float2(a.z, a.w));
    u.h[2] = __float22bfloat162_rn(make_float2(b.x, b.y));
    u.h[3] = __float22bfloat162_rn(make_float2(b.z, b.w));
    return u.s;
}

// ------- K1: binning ONLY (R9's proven LDS-ballot block), 90 blocks ----------
__global__ __launch_bounds__(1024)
void k_bin(const int* __restrict__ labels, int* __restrict__ idx, int* __restrict__ cnt) {
    __shared__ int lab[BB];       // 64 KiB label cache
    __shared__ int wcnt[16];

    int t = threadIdx.x, w = t >> 6, lane = t & 63;
    int c = blockIdx.x;
    for (int j = t; j < BB / 4; j += 1024)          // coalesced int4 load
        ((int4*)lab)[j] = ((const int4*)labels)[j];
    __syncthreads();

    int seg4 = w * (BB / 4 / 16);                   // 256 int4s per wave
    int cw = 0;
#pragma unroll
    for (int jj = 0; jj < 4; jj++) {
        int4 v = ((int4*)lab)[seg4 + jj * 64 + lane];
        cw += (v.x == c) + (v.y == c) + (v.z == c) + (v.w == c);
    }
#pragma unroll
    for (int m = 1; m < 64; m <<= 1) cw += __shfl_xor(cw, m, 64);
    if (lane == 0) wcnt[w] = cw;
    __syncthreads();
    int pos = c * BUCKET;
    for (int ww = 0; ww < w; ww++) pos += wcnt[ww];
#pragma unroll
    for (int jj = 0; jj < 4; jj++) {
        int4 v = ((int4*)lab)[seg4 + jj * 64 + lane];
        int gbase = (seg4 + jj * 64 + lane) * 4;
        { bool m = (v.x == c); unsigned long long k = __ballot(m);
          if (m) idx[pos + __popcll(k & ((1ull << lane) - 1ull))] = gbase;     pos += __popcll(k); }
        { bool m = (v.y == c); unsigned long long k = __ballot(m);
          if (m) idx[pos + __popcll(k & ((1ull << lane) - 1ull))] = gbase + 1; pos += __popcll(k); }
        { bool m = (v.z == c); unsigned long long k = __ballot(m);
          if (m) idx[pos + __popcll(k & ((1ull << lane) - 1ull))] = gbase + 2; pos += __popcll(k); }
        { bool m = (v.w == c); unsigned long long k = __ballot(m);
          if (m) idx[pos + __popcll(k & ((1ull << lane) - 1ull))] = gbase + 3; pos += __popcll(k); }
    }
    if (t == 0) {
        int s = 0;
#pragma unroll
        for (int i = 0; i < 16; i++) s += wcnt[i];
        cnt[c] = s;
    }
}

// ------- K2: main — in-block center norm (f32 direct), prefetched gather -----
// R13's proven chunk body; c_lds built from raw centers (no cni image);
// first chunk's 16 x-loads issued BEFORE the norm work (T14 overlap).
__launch_bounds__(256, 2)
__global__ void k_main(const float* __restrict__ x,
                       const float* __restrict__ centers,
                       const int* __restrict__ cnt,
                       const int* __restrict__ idx,
                       float* __restrict__ partials) {
    __shared__ __align__(16) short c_lds[KC * DD];   // 32 KiB bf16, XOR-swizzled
    __shared__ __align__(16) short x_lds[32 * DD];   // 32 KiB bf16, XOR-swizzled
    __shared__ float S_lds[32][33];
    __shared__ float xinv[32];
    __shared__ float red4[4];

    int c = blockIdx.x >> 3;
    int p = blockIdx.x & 7;
    int n = cnt[c];
    int nch = (n + 31) >> 5;
    int t = threadIdx.x, w = t >> 6, lane = t & 63;
    float loss_acc = 0.f;

    if (p < nch) {
        int base = c * BUCKET;
        int row8 = t >> 3, l8 = t & 7;            // 8 threads per (sample|center) row
        int mrow = ((w & 1) << 4) + (lane & 15);
        int nrow = ((w >> 1) << 4) + (lane & 15);

        // ---- issue FIRST chunk's x loads (overlap with center norm below) ----
        float4 xva[8], xvb[8];
        {
            int off = p << 5;
            int rem = n - off;
            int r = (row8 < rem) ? row8 : (rem - 1);
            int g = idx[base + off + r];
            const float4* src = (const float4*)(x + (size_t)g * DD);
#pragma unroll
            for (int jj = 0; jj < 8; jj++) {
                xva[jj] = src[2 * l8 + 16 * jj];
                xvb[jj] = src[2 * l8 + 16 * jj + 1];
            }
        }

        // ---- center norm: batch-load 16 float4, norm, scale, pack, c_lds ----
        {
            const float4* csrc = (const float4*)(centers + ((size_t)c * KC + row8) * DD);
            float4 cva[8], cvb[8];
#pragma unroll
            for (int jj = 0; jj < 8; jj++) {
                cva[jj] = csrc[2 * l8 + 16 * jj];
                cvb[jj] = csrc[2 * l8 + 16 * jj + 1];
            }
            float s = 0.f;
#pragma unroll
            for (int jj = 0; jj < 8; jj++) {
                float4 a = cva[jj], b4 = cvb[jj];
                s += a.x * a.x + a.y * a.y + a.z * a.z + a.w * a.w
                   + b4.x * b4.x + b4.y * b4.y + b4.z * b4.z + b4.w * b4.w;
            }
#pragma unroll
            for (int m = 1; m < 8; m <<= 1) s += __shfl_xor(s, m, 64);
            float sc = rsqrtf(s + 1e-12f);
#pragma unroll
            for (int jj = 0; jj < 8; jj++) {
                int c16 = l8 + 8 * jj;             // 16B bf16 chunk 0..63
                *(short8*)&c_lds[row8 * DD + ((c16 ^ (row8 & 7)) << 3)]
                    = pack8s(sc, cva[jj], cvb[jj]);
            }
        }

        for (int ch = p; ch < nch; ch += NP) {
            int off = ch << 5;
            int rem = n - off;                    // > 0

            // ---- consume prefetched x: norm + cvt + x_lds ----
            {
                float nrm = 0.f;
#pragma unroll
                for (int jj = 0; jj < 8; jj++) {
                    int cc = l8 + 8 * jj;          // 16B bf16 chunk 0..63
                    float4 a = xva[jj], b4 = xvb[jj];
                    nrm += a.x * a.x + a.y * a.y + a.z * a.z + a.w * a.w
                         + b4.x * b4.x + b4.y * b4.y + b4.z * b4.z + b4.w * b4.w;
                    *(short8*)&x_lds[row8 * DD + ((cc ^ (row8 & 7)) << 3)] = pack8(a, b4);
                }
#pragma unroll
                for (int m = 1; m < 8; m <<= 1) nrm += __shfl_xor(nrm, m, 64);
                if (l8 == 0) xinv[row8] = rsqrtf(nrm + 1e-12f);
            }
            __syncthreads();                       // c_lds (1st iter) + x_lds ready

            // ---- MFMA: S[32 samples][32 k] in 4 wave-quadrants ----
            fx4 acc = {0.f, 0.f, 0.f, 0.f};
#pragma unroll
            for (int ks = 0; ks < 16; ks++) {
                int c16a = ks * 4 + (lane >> 4);
                short8 av = *(const short8*)&x_lds[mrow * DD + ((c16a ^ (mrow & 7)) << 3)];
                short8 bv = *(const short8*)&c_lds[nrow * DD + ((c16a ^ (nrow & 7)) << 3)];
                acc = __builtin_amdgcn_mfma_f32_16x16x32_bf16(av, bv, acc, 0, 0, 0);
            }
#pragma unroll
            for (int j = 0; j < 4; j++) {
                int r = ((w & 1) << 4) + ((lane >> 4) << 2) + j;   // C/D row
                int col = ((w >> 1) << 4) + (lane & 15);           // C/D col
                S_lds[r][col] = acc[j];
            }

            // ---- prefetch NEXT chunk's x loads (issue before barriers) ----
            if (ch + NP < nch) {
                int off2 = (ch + NP) << 5;
                int rem2 = n - off2;
                int r2 = (row8 < rem2) ? row8 : (rem2 - 1);
                int g2 = idx[base + off2 + r2];
                const float4* src2 = (const float4*)(x + (size_t)g2 * DD);
#pragma unroll
                for (int jj = 0; jj < 8; jj++) {
                    xva[jj] = src2[2 * l8 + 16 * jj];
                    xvb[jj] = src2[2 * l8 + 16 * jj + 1];
                }
            }
            __syncthreads();                       // S_lds ready

            // ---- MAX-FREE softmax over K=32 (cos in [-1,1]; __expf) ----
            {
                float xv = xinv[row8];
                int q4 = l8 << 2;
                float s0 = S_lds[row8][q4 + 0] * xv;
                float s1 = S_lds[row8][q4 + 1] * xv;
                float s2 = S_lds[row8][q4 + 2] * xv;
                float s3 = S_lds[row8][q4 + 3] * xv;
                float e0 = __expf(s0), e1 = __expf(s1);
                float e2 = __expf(s2), e3 = __expf(s3);
                float Z = e0 + e1 + e2 + e3;
                float num = e0 * (1.f - s0) + e1 * (1.f - s1)
                          + e2 * (1.f - s2) + e3 * (1.f - s3);
#pragma unroll
                for (int m = 1; m < 8; m <<= 1) {
                    Z += __shfl_xor(Z, m, 64);
                    num += __shfl_xor(num, m, 64);
                }
                if (l8 == 0 && row8 < rem) loss_acc += num / Z;
            }
            __syncthreads();   // protect x_lds/S_lds before next chunk
        }
    }

    // ---- slim per-wave tail reduce (1 barrier) ----
#pragma unroll
    for (int m = 1; m < 64; m <<= 1) loss_acc += __shfl_xor(loss_acc, m, 64);
    if (lane == 0) red4[w] = loss_acc;
    __syncthreads();
    if (t == 0) partials[blockIdx.x] = red4[0] + red4[1] + red4[2] + red4[3];
}

// ------- K3: deterministic final mean over 720 block partials ----------------
__global__ void k_final(const float* __restrict__ partials, float* __restrict__ out) {
    __shared__ float red[256];
    int t = threadIdx.x;
    float s = 0.f;
    for (int i = t; i < NCLS * NP; i += 256) s += partials[i];
    red[t] = s;
    __syncthreads();
    for (int h = 128; h > 0; h >>= 1) {
        if (t < h) red[t] += red[t + h];
        __syncthreads();
    }
    if (t == 0) out[0] = red[0] * (1.0f / (float)BB);
}

extern "C" void kernel_launch(void* const* d_in, const int* in_sizes, int n_in,
                              void* d_out, int out_size, void* d_ws, size_t ws_size,
                              hipStream_t stream) {
    const float* x       = (const float*)d_in[0];
    const int*   labels  = (const int*)d_in[1];
    const float* centers = (const float*)d_in[2];
    float* out = (float*)d_out;

    char* ws = (char*)d_ws;
    int*   idx      = (int*)(ws + 0);               // 90*512 ints = 184,320 B
    int*   cnt      = (int*)(ws + 184320);          // 90 ints
    float* partials = (float*)(ws + 196608);        // 720 floats (all written)

    k_bin<<<NCLS, 1024, 0, stream>>>(labels, idx, cnt);
    k_main<<<NCLS * NP, 256, 0, stream>>>(x, centers, cnt, idx, partials);
    k_final<<<1, 256, 0, stream>>>(partials, out);
}

// Round 19
// 24.361 us; speedup vs baseline: 1.8084x; 1.1738x over previous
//
#include <hip/hip_runtime.h>
#include <hip/hip_bf16.h>

// Problem constants (match reference)
#define BB 16384
#define DD 512
#define NCLS 90
#define KC 32
#define BUCKET 512   // max samples per class (mean 182, +24 sigma headroom)
#define NP 4         // partition blocks per class (chunk = 32 samples)

typedef __attribute__((ext_vector_type(8))) short short8;   // 8 bf16 (4 VGPRs)
typedef __attribute__((ext_vector_type(4))) float fx4;      // MFMA accumulator

// pack 8 f32 -> 8 bf16 (RNE, v_cvt_pk_bf16_f32), with / without scale
static __device__ __forceinline__ short8 pack8s(float sc, float4 a, float4 b) {
    union { __hip_bfloat162 h[4]; short8 s; } u;
    u.h[0] = __float22bfloat162_rn(make_float2(a.x * sc, a.y * sc));
    u.h[1] = __float22bfloat162_rn(make_float2(a.z * sc, a.w * sc));
    u.h[2] = __float22bfloat162_rn(make_float2(b.x * sc, b.y * sc));
    u.h[3] = __float22bfloat162_rn(make_float2(b.z * sc, b.w * sc));
    return u.s;
}
static __device__ __forceinline__ short8 pack8(float4 a, float4 b) {
    union { __hip_bfloat162 h[4]; short8 s; } u;
    u.h[0] = __float22bfloat162_rn(make_float2(a.x, a.y));
    u.h[1] = __float22bfloat162_rn(make_float2(a.z, a.w));
    u.h[2] = __float22bfloat162_rn(make_float2(b.x, b.y));
    u.h[3] = __float22bfloat162_rn(make_float2(b.z, b.w));
    return u.s;
}

// ------- K1: binning ONLY (R9's proven LDS-ballot block), 90 blocks ----------
__global__ __launch_bounds__(1024)
void k_bin(const int* __restrict__ labels, int* __restrict__ idx, int* __restrict__ cnt) {
    __shared__ int lab[BB];       // 64 KiB label cache
    __shared__ int wcnt[16];

    int t = threadIdx.x, w = t >> 6, lane = t & 63;
    int c = blockIdx.x;
    for (int j = t; j < BB / 4; j += 1024)          // coalesced int4 load
        ((int4*)lab)[j] = ((const int4*)labels)[j];
    __syncthreads();

    int seg4 = w * (BB / 4 / 16);                   // 256 int4s per wave
    int cw = 0;
#pragma unroll
    for (int jj = 0; jj < 4; jj++) {
        int4 v = ((int4*)lab)[seg4 + jj * 64 + lane];
        cw += (v.x == c) + (v.y == c) + (v.z == c) + (v.w == c);
    }
#pragma unroll
    for (int m = 1; m < 64; m <<= 1) cw += __shfl_xor(cw, m, 64);
    if (lane == 0) wcnt[w] = cw;
    __syncthreads();
    int pos = c * BUCKET;
    for (int ww = 0; ww < w; ww++) pos += wcnt[ww];
#pragma unroll
    for (int jj = 0; jj < 4; jj++) {
        int4 v = ((int4*)lab)[seg4 + jj * 64 + lane];
        int gbase = (seg4 + jj * 64 + lane) * 4;
        { bool m = (v.x == c); unsigned long long k = __ballot(m);
          if (m) idx[pos + __popcll(k & ((1ull << lane) - 1ull))] = gbase;     pos += __popcll(k); }
        { bool m = (v.y == c); unsigned long long k = __ballot(m);
          if (m) idx[pos + __popcll(k & ((1ull << lane) - 1ull))] = gbase + 1; pos += __popcll(k); }
        { bool m = (v.z == c); unsigned long long k = __ballot(m);
          if (m) idx[pos + __popcll(k & ((1ull << lane) - 1ull))] = gbase + 2; pos += __popcll(k); }
        { bool m = (v.w == c); unsigned long long k = __ballot(m);
          if (m) idx[pos + __popcll(k & ((1ull << lane) - 1ull))] = gbase + 3; pos += __popcll(k); }
    }
    if (t == 0) {
        int s = 0;
#pragma unroll
        for (int i = 0; i < 16; i++) s += wcnt[i];
        cnt[c] = s;
    }
}

// ------- K2: main — in-block center norm, 2-chunk pipeline (NP=4) ------------
__launch_bounds__(256, 2)
__global__ void k_main(const float* __restrict__ x,
                       const float* __restrict__ centers,
                       const int* __restrict__ cnt,
                       const int* __restrict__ idx,
                       float* __restrict__ partials) {
    __shared__ __align__(16) short c_lds[KC * DD];   // 32 KiB bf16, XOR-swizzled
    __shared__ __align__(16) short x_lds[32 * DD];   // 32 KiB bf16, XOR-swizzled
    __shared__ float S_lds[32][33];
    __shared__ float xinv[32];
    __shared__ float red4[4];

    int c = blockIdx.x >> 2;
    int p = blockIdx.x & 3;
    int n = cnt[c];
    int nch = (n + 31) >> 5;
    int t = threadIdx.x, w = t >> 6, lane = t & 63;
    float loss_acc = 0.f;

    if (p < nch) {
        int base = c * BUCKET;
        int row8 = t >> 3, l8 = t & 7;            // 8 threads per (sample|center) row
        int mrow = ((w & 1) << 4) + (lane & 15);
        int nrow = ((w >> 1) << 4) + (lane & 15);

        // ---- issue FIRST chunk's x loads (overlap with center norm below) ----
        float4 xva[8], xvb[8];
        {
            int off = p << 5;
            int rem = n - off;
            int r = (row8 < rem) ? row8 : (rem - 1);
            int g = idx[base + off + r];
            const float4* src = (const float4*)(x + (size_t)g * DD);
#pragma unroll
            for (int jj = 0; jj < 8; jj++) {
                xva[jj] = src[2 * l8 + 16 * jj];
                xvb[jj] = src[2 * l8 + 16 * jj + 1];
            }
        }

        // ---- center norm: batch-load 16 float4, norm, scale, pack, c_lds ----
        {
            const float4* csrc = (const float4*)(centers + ((size_t)c * KC + row8) * DD);
            float4 cva[8], cvb[8];
#pragma unroll
            for (int jj = 0; jj < 8; jj++) {
                cva[jj] = csrc[2 * l8 + 16 * jj];
                cvb[jj] = csrc[2 * l8 + 16 * jj + 1];
            }
            float s = 0.f;
#pragma unroll
            for (int jj = 0; jj < 8; jj++) {
                float4 a = cva[jj], b4 = cvb[jj];
                s += a.x * a.x + a.y * a.y + a.z * a.z + a.w * a.w
                   + b4.x * b4.x + b4.y * b4.y + b4.z * b4.z + b4.w * b4.w;
            }
#pragma unroll
            for (int m = 1; m < 8; m <<= 1) s += __shfl_xor(s, m, 64);
            float sc = rsqrtf(s + 1e-12f);
#pragma unroll
            for (int jj = 0; jj < 8; jj++) {
                int c16 = l8 + 8 * jj;             // 16B bf16 chunk 0..63
                *(short8*)&c_lds[row8 * DD + ((c16 ^ (row8 & 7)) << 3)]
                    = pack8s(sc, cva[jj], cvb[jj]);
            }
        }

        for (int ch = p; ch < nch; ch += NP) {
            int off = ch << 5;
            int rem = n - off;                    // > 0

            // ---- consume prefetched x: norm + cvt + x_lds ----
            {
                float nrm = 0.f;
#pragma unroll
                for (int jj = 0; jj < 8; jj++) {
                    int cc = l8 + 8 * jj;          // 16B bf16 chunk 0..63
                    float4 a = xva[jj], b4 = xvb[jj];
                    nrm += a.x * a.x + a.y * a.y + a.z * a.z + a.w * a.w
                         + b4.x * b4.x + b4.y * b4.y + b4.z * b4.z + b4.w * b4.w;
                    *(short8*)&x_lds[row8 * DD + ((cc ^ (row8 & 7)) << 3)] = pack8(a, b4);
                }
#pragma unroll
                for (int m = 1; m < 8; m <<= 1) nrm += __shfl_xor(nrm, m, 64);
                if (l8 == 0) xinv[row8] = rsqrtf(nrm + 1e-12f);
            }
            __syncthreads();                       // c_lds (1st iter) + x_lds ready

            // ---- MFMA: S[32 samples][32 k] in 4 wave-quadrants ----
            fx4 acc = {0.f, 0.f, 0.f, 0.f};
#pragma unroll
            for (int ks = 0; ks < 16; ks++) {
                int c16a = ks * 4 + (lane >> 4);
                short8 av = *(const short8*)&x_lds[mrow * DD + ((c16a ^ (mrow & 7)) << 3)];
                short8 bv = *(const short8*)&c_lds[nrow * DD + ((c16a ^ (nrow & 7)) << 3)];
                acc = __builtin_amdgcn_mfma_f32_16x16x32_bf16(av, bv, acc, 0, 0, 0);
            }
#pragma unroll
            for (int j = 0; j < 4; j++) {
                int r = ((w & 1) << 4) + ((lane >> 4) << 2) + j;   // C/D row
                int col = ((w >> 1) << 4) + (lane & 15);           // C/D col
                S_lds[r][col] = acc[j];
            }

            // ---- prefetch NEXT chunk's x into registers (survives barriers) --
            if (ch + NP < nch) {
                int off2 = (ch + NP) << 5;
                int rem2 = n - off2;
                int r2 = (row8 < rem2) ? row8 : (rem2 - 1);
                int g2 = idx[base + off2 + r2];
                const float4* src2 = (const float4*)(x + (size_t)g2 * DD);
#pragma unroll
                for (int jj = 0; jj < 8; jj++) {
                    xva[jj] = src2[2 * l8 + 16 * jj];
                    xvb[jj] = src2[2 * l8 + 16 * jj + 1];
                }
            }
            __syncthreads();                       // S_lds ready

            // ---- MAX-FREE softmax over K=32 (cos in [-1,1]; __expf) ----
            {
                float xv = xinv[row8];
                int q4 = l8 << 2;
                float s0 = S_lds[row8][q4 + 0] * xv;
                float s1 = S_lds[row8][q4 + 1] * xv;
                float s2 = S_lds[row8][q4 + 2] * xv;
                float s3 = S_lds[row8][q4 + 3] * xv;
                float e0 = __expf(s0), e1 = __expf(s1);
                float e2 = __expf(s2), e3 = __expf(s3);
                float Z = e0 + e1 + e2 + e3;
                float num = e0 * (1.f - s0) + e1 * (1.f - s1)
                          + e2 * (1.f - s2) + e3 * (1.f - s3);
#pragma unroll
                for (int m = 1; m < 8; m <<= 1) {
                    Z += __shfl_xor(Z, m, 64);
                    num += __shfl_xor(num, m, 64);
                }
                if (l8 == 0 && row8 < rem) loss_acc += num / Z;
            }
            __syncthreads();   // protect x_lds/S_lds before next chunk
        }
    }

    // ---- slim per-wave tail reduce (1 barrier) ----
#pragma unroll
    for (int m = 1; m < 64; m <<= 1) loss_acc += __shfl_xor(loss_acc, m, 64);
    if (lane == 0) red4[w] = loss_acc;
    __syncthreads();
    if (t == 0) partials[blockIdx.x] = red4[0] + red4[1] + red4[2] + red4[3];
}

// ------- K3: deterministic final mean over 360 block partials ----------------
__global__ void k_final(const float* __restrict__ partials, float* __restrict__ out) {
    __shared__ float red[256];
    int t = threadIdx.x;
    float s = 0.f;
    for (int i = t; i < NCLS * NP; i += 256) s += partials[i];
    red[t] = s;
    __syncthreads();
    for (int h = 128; h > 0; h >>= 1) {
        if (t < h) red[t] += red[t + h];
        __syncthreads();
    }
    if (t == 0) out[0] = red[0] * (1.0f / (float)BB);
}

extern "C" void kernel_launch(void* const* d_in, const int* in_sizes, int n_in,
                              void* d_out, int out_size, void* d_ws, size_t ws_size,
                              hipStream_t stream) {
    const float* x       = (const float*)d_in[0];
    const int*   labels  = (const int*)d_in[1];
    const float* centers = (const float*)d_in[2];
    float* out = (float*)d_out;

    char* ws = (char*)d_ws;
    int*   idx      = (int*)(ws + 0);               // 90*512 ints = 184,320 B
    int*   cnt      = (int*)(ws + 184320);          // 90 ints
    float* partials = (float*)(ws + 196608);        // 360 floats (all written)

    k_bin<<<NCLS, 1024, 0, stream>>>(labels, idx, cnt);
    k_main<<<NCLS * NP, 256, 0, stream>>>(x, centers, cnt, idx, partials);
    k_final<<<1, 256, 0, stream>>>(partials, out);
}